// Round 9
// baseline (218.412 us; speedup 1.0000x reference)
//
#include <hip/hip_runtime.h>
#include <hip/hip_bf16.h>
#include <math.h>

typedef __hip_bfloat16 bf16;
typedef __bf16 bf16x8 __attribute__((ext_vector_type(8)));
typedef float  f32x4  __attribute__((ext_vector_type(4)));

#define NB 8
#define SL 1024
#define DD 256
#define NF 11
#define RPB 8

#define AS_G __attribute__((address_space(1)))
#define AS_L __attribute__((address_space(3)))

// ---------- fragment loaders ----------
__device__ __forceinline__ bf16x8 ldfrag(const bf16* p) {
  return *reinterpret_cast<const bf16x8*>(p);
}
__device__ __forceinline__ bf16x8 ldfrag(const float* p) {
  const float4 a = *reinterpret_cast<const float4*>(p);
  const float4 b = *reinterpret_cast<const float4*>(p + 4);
  bf16x8 r;
  r[0] = (__bf16)a.x; r[1] = (__bf16)a.y; r[2] = (__bf16)a.z; r[3] = (__bf16)a.w;
  r[4] = (__bf16)b.x; r[5] = (__bf16)b.y; r[6] = (__bf16)b.z; r[7] = (__bf16)b.w;
  return r;
}
__device__ __forceinline__ unsigned short us(float f) {
  bf16 h = __float2bfloat16(f);
  return *reinterpret_cast<unsigned short*>(&h);
}
__device__ __forceinline__ float tanh_fast(float x) {
  return 1.f - 2.f / (__expf(2.f * x) + 1.f);
}

// ---------- stage R rows x 64 k into XOR-swizzled LDS ----------
template<int R>
__device__ __forceinline__ void stage_t(const float* __restrict__ g, int ld,
                                        bf16* __restrict__ s, int tid) {
#pragma unroll
  for (int it = 0; it < R / 32; ++it) {
    const int cid = it * 256 + tid;
    const int row = cid >> 3, c16 = cid & 7;
    bf16x8 v = ldfrag(g + (size_t)row * ld + c16 * 8);
    *reinterpret_cast<bf16x8*>(s + row * 64 + ((c16 ^ (row & 7)) << 3)) = v;
  }
}
template<int R>
__device__ __forceinline__ void stage_t(const bf16* __restrict__ g, int ld,
                                        bf16* __restrict__ s, int tid) {
  const int wbase = tid & ~63;
#pragma unroll
  for (int it = 0; it < R / 32; ++it) {
    const int cid = it * 256 + tid;
    const int row = cid >> 3, sc = cid & 7;
    const int c16 = sc ^ (row & 7);
    const bf16* src = g + (size_t)row * ld + c16 * 8;
    bf16* dst = s + (size_t)(it * 256 + wbase) * 8;
    __builtin_amdgcn_global_load_lds((const AS_G void*)src, (AS_L void*)dst, 16, 0, 0);
  }
}

// ---------- compute: 64x128 tile (4 waves x 64x32) from sA 64x64 + sB 128x64 ----------
__device__ __forceinline__ void compute_64x128(const bf16* __restrict__ sA,
                                               const bf16* __restrict__ sB,
                                               int lane, int wave, f32x4 acc[4][2]) {
  const int n15 = lane & 15, quad = lane >> 4;
  const int wn = wave * 32;
#pragma unroll
  for (int kc = 0; kc < 2; ++kc) {
    const int c16 = kc * 4 + quad;
    bf16x8 aF[4], bF[2];
#pragma unroll
    for (int t = 0; t < 4; ++t) {
      const int ra = t * 16 + n15;
      aF[t] = *reinterpret_cast<const bf16x8*>(sA + ra * 64 + ((c16 ^ (ra & 7)) << 3));
    }
#pragma unroll
    for (int t = 0; t < 2; ++t) {
      const int rb = wn + t * 16 + n15;
      bF[t] = *reinterpret_cast<const bf16x8*>(sB + rb * 64 + ((c16 ^ (rb & 7)) << 3));
    }
#pragma unroll
    for (int ti = 0; ti < 4; ++ti)
#pragma unroll
      for (int tj = 0; tj < 2; ++tj)
        acc[ti][tj] = __builtin_amdgcn_mfma_f32_16x16x32_bf16(aF[ti], bF[tj], acc[ti][tj], 0, 0, 0);
  }
}

// ---------- dual-B compute: shared aF, two B tiles ----------
__device__ __forceinline__ void compute_64x128x2(const bf16* __restrict__ sA,
                                                 const bf16* __restrict__ sB1,
                                                 const bf16* __restrict__ sB2,
                                                 int lane, int wave,
                                                 f32x4 acc1[4][2], f32x4 acc2[4][2]) {
  const int n15 = lane & 15, quad = lane >> 4;
  const int wn = wave * 32;
#pragma unroll
  for (int kc = 0; kc < 2; ++kc) {
    const int c16 = kc * 4 + quad;
    bf16x8 aF[4], b1F[2], b2F[2];
#pragma unroll
    for (int t = 0; t < 4; ++t) {
      const int ra = t * 16 + n15;
      aF[t] = *reinterpret_cast<const bf16x8*>(sA + ra * 64 + ((c16 ^ (ra & 7)) << 3));
    }
#pragma unroll
    for (int t = 0; t < 2; ++t) {
      const int rb = wn + t * 16 + n15;
      const int off = rb * 64 + ((c16 ^ (rb & 7)) << 3);
      b1F[t] = *reinterpret_cast<const bf16x8*>(sB1 + off);
      b2F[t] = *reinterpret_cast<const bf16x8*>(sB2 + off);
    }
#pragma unroll
    for (int ti = 0; ti < 4; ++ti)
#pragma unroll
      for (int tj = 0; tj < 2; ++tj) {
        acc1[ti][tj] = __builtin_amdgcn_mfma_f32_16x16x32_bf16(aF[ti], b1F[tj], acc1[ti][tj], 0, 0, 0);
        acc2[ti][tj] = __builtin_amdgcn_mfma_f32_16x16x32_bf16(aF[ti], b2F[tj], acc2[ti][tj], 0, 0, 0);
      }
  }
}

// ---------- single-B GEMM driver ----------
template<typename TA, typename TB>
__device__ __forceinline__ void gemm_64x128(const TA* __restrict__ A, int lda,
                                            const TB* __restrict__ B, int ldb, int K,
                                            bf16* s, int tid, f32x4 acc[4][2]) {
  const int lane = tid & 63, wave = tid >> 6;
  bf16* sA = s;
  bf16* sB = s + 4096;
  for (int k0 = 0; k0 < K; k0 += 64) {
    stage_t<64>(A + k0, lda, sA, tid);
    stage_t<128>(B + k0, ldb, sB, tid);
    __syncthreads();
    compute_64x128(sA, sB, lane, wave, acc);
    __syncthreads();
  }
}

__device__ __forceinline__ float wred_sum(float v) {
#pragma unroll
  for (int o = 32; o > 0; o >>= 1) v += __shfl_xor(v, o, 64);
  return v;
}

// ---------- K0: Wc = w_fc @ w_vs (f32, 256x256) ----------
__global__ __launch_bounds__(256) void k_wc(const float* __restrict__ wfc,
                                            const float* __restrict__ wvs,
                                            float* __restrict__ Wc)
{
  const int o = blockIdx.x, m = threadIdx.x;
  const float* fr = wfc + (size_t)o * DD;
  float acc = 0.f;
#pragma unroll 8
  for (int i = 0; i < DD; ++i)
    acc += fr[i] * wvs[(size_t)i * DD + m];
  Wc[(size_t)o * DD + m] = acc;
}

// ---------- K1: projections, A-shared pairs: z0={q:wqs,wqs2}, z1={k:wks,wks2}, z2={v:Wc} ----------
__global__ __launch_bounds__(256) void k_proj(
    const float* __restrict__ q, const float* __restrict__ k, const float* __restrict__ v,
    const float* __restrict__ wqs, const float* __restrict__ wks, const float* __restrict__ Wc,
    const float* __restrict__ wqs2, const float* __restrict__ wks2,
    bf16* __restrict__ qq, bf16* __restrict__ kk,
    bf16* __restrict__ vpwt, bf16* __restrict__ q2t, bf16* __restrict__ k2t)
{
  __shared__ bf16 smem[20480];   // sA 4096 + sB1 8192 + sB2 8192
  const int tid = threadIdx.x, lane = tid & 63, wave = tid >> 6;
  const int z = blockIdx.z;
  const float* A  = (z == 0) ? q : (z == 1) ? k : v;
  const float* W1 = (z == 0) ? wqs : (z == 1) ? wks : Wc;
  const float* W2 = (z == 0) ? wqs2 : wks2;   // unused for z==2
  const bool dual = (z < 2);
  const int rowBase = blockIdx.x * 64;
  const int colBase = blockIdx.y * 128;
  bf16* sA = smem;
  bf16* sB1 = smem + 4096;
  bf16* sB2 = smem + 12288;
  f32x4 acc1[4][2] = {}, acc2[4][2] = {};
  const float* Ap  = A  + (size_t)rowBase * DD;
  const float* B1p = W1 + (size_t)colBase * DD;
  const float* B2p = W2 + (size_t)colBase * DD;
  for (int k0 = 0; k0 < DD; k0 += 64) {
    stage_t<64>(Ap + k0, DD, sA, tid);
    stage_t<128>(B1p + k0, DD, sB1, tid);
    if (dual) stage_t<128>(B2p + k0, DD, sB2, tid);
    __syncthreads();
    if (dual) compute_64x128x2(sA, sB1, sB2, lane, wave, acc1, acc2);
    else      compute_64x128(sA, sB1, lane, wave, acc1);
    __syncthreads();
  }
  const int n15 = lane & 15, quad = lane >> 4;
  const int wn = wave * 32;
  const int bb = rowBase >> 10, rowInB = rowBase & 1023;
  if (dual) {
    // acc1 -> qq/kk cols 0..255 (row-major, ld 512)
    bf16* O1 = (z == 0) ? qq : kk;
#pragma unroll
    for (int ti = 0; ti < 4; ++ti)
#pragma unroll
      for (int tj = 0; tj < 2; ++tj)
#pragma unroll
        for (int r = 0; r < 4; ++r) {
          int row = rowBase + ti * 16 + quad * 4 + r;
          int col = colBase + wn + tj * 16 + n15;
          O1[(size_t)row * 512 + col] = __float2bfloat16(acc1[ti][tj][r]);
        }
    // acc2 -> q2t/k2t transposed [b][d][l]
    bf16* O2 = (z == 0) ? q2t : k2t;
#pragma unroll
    for (int ti = 0; ti < 4; ++ti)
#pragma unroll
      for (int tj = 0; tj < 2; ++tj) {
        int l0  = rowInB + ti * 16 + quad * 4;
        int col = colBase + wn + tj * 16 + n15;
        ushort4 pk = make_ushort4(us(acc2[ti][tj][0]), us(acc2[ti][tj][1]),
                                  us(acc2[ti][tj][2]), us(acc2[ti][tj][3]));
        *reinterpret_cast<ushort4*>(&O2[((size_t)bb * DD + col) * SL + l0]) = pk;
      }
  } else {
    // acc1 -> vpwt transposed [b][d][l]
#pragma unroll
    for (int ti = 0; ti < 4; ++ti)
#pragma unroll
      for (int tj = 0; tj < 2; ++tj) {
        int l0  = rowInB + ti * 16 + quad * 4;
        int col = colBase + wn + tj * 16 + n15;
        ushort4 pk = make_ushort4(us(acc1[ti][tj][0]), us(acc1[ti][tj][1]),
                                  us(acc1[ti][tj][2]), us(acc1[ti][tj][3]));
        *reinterpret_cast<ushort4*>(&vpwt[((size_t)bb * DD + col) * SL + l0]) = pk;
      }
  }
}

// ---------- K2: feature-affinity softmax, RPB rows per block ----------
__global__ __launch_bounds__(256) void k_fa(const float* __restrict__ x,
                                            const float* __restrict__ fi_g,
                                            const int* __restrict__ lens,
                                            bf16* __restrict__ fa)
{
  __shared__ __align__(16) float sx[SL * NF];
  __shared__ float sredS[4][RPB];
  const int tid = threadIdx.x, wave = tid >> 6;
  const int b  = blockIdx.x >> 7;
  const int i0 = (blockIdx.x & 127) * RPB;
  {
    const float4* src = reinterpret_cast<const float4*>(x + (size_t)b * SL * NF);
    float4* dst = reinterpret_cast<float4*>(sx);
#pragma unroll
    for (int it = 0; it < 11; ++it) dst[it * 256 + tid] = src[it * 256 + tid];
  }
  float fiv[NF];
#pragma unroll
  for (int f = 0; f < NF; ++f) fiv[f] = fi_g[f];
  const int len = lens[b];
  __syncthreads();
  float xi[RPB][NF];
#pragma unroll
  for (int i = 0; i < RPB; ++i)
#pragma unroll
    for (int f = 0; f < NF; ++f) xi[i][f] = sx[(i0 + i) * NF + f];
  float e[RPB][4];
  float ps[RPB];
#pragma unroll
  for (int i = 0; i < RPB; ++i) ps[i] = 0.f;
#pragma unroll
  for (int t = 0; t < 4; ++t) {
    const int j = tid + t * 256;
    const bool valid = (t < 2) || (j < len);
    float xj[NF];
#pragma unroll
    for (int f = 0; f < NF; ++f) xj[f] = sx[j * NF + f];
#pragma unroll
    for (int i = 0; i < RPB; ++i) {
      float a = 0.f;
#pragma unroll
      for (int f = 0; f < NF; ++f) a += fabsf(xi[i][f] - xj[f]) * fiv[f];
      float ev = valid ? __expf(a) : 0.f;
      e[i][t] = ev;
      ps[i] += ev;
    }
  }
#pragma unroll
  for (int i = 0; i < RPB; ++i) {
    float wsv = wred_sum(ps[i]);
    if ((tid & 63) == 0) sredS[wave][i] = wsv;
  }
  __syncthreads();
  bf16* out = fa + (size_t)b * SL * SL + (size_t)i0 * SL;
#pragma unroll
  for (int i = 0; i < RPB; ++i) {
    const float inv = 1.f / (sredS[0][i] + sredS[1][i] + sredS[2][i] + sredS[3][i]);
#pragma unroll
    for (int t = 0; t < 4; ++t)
      out[(size_t)i * SL + tid + t * 256] = __float2bfloat16(e[i][t] * inv);
  }
}

// ---------- K3: {q2f,k2f} = fa @ {q2,k2}, A shared -> qq/kk cols 256..511 ----------
__global__ __launch_bounds__(256) void k_famul(const bf16* __restrict__ fa,
                                               const bf16* __restrict__ q2t,
                                               const bf16* __restrict__ k2t,
                                               bf16* __restrict__ qq,
                                               bf16* __restrict__ kk)
{
  __shared__ bf16 smem[20480];
  const int tid = threadIdx.x, lane = tid & 63, wave = tid >> 6;
  // grid (16,2,8); swizzle so batch ~ XCD
  const int flat = blockIdx.x + 16 * blockIdx.y + 32 * blockIdx.z;
  const int lid  = (flat & 7) * 32 + (flat >> 3);
  const int bx = lid & 15, by = (lid >> 4) & 1, bz = lid >> 5;
  const int b = bz;
  const int iBase = bx * 64, dBase = by * 128;
  const bf16* A  = fa  + (size_t)b * SL * SL + (size_t)iBase * SL;
  const bf16* B1 = q2t + (size_t)b * DD * SL + (size_t)dBase * SL;
  const bf16* B2 = k2t + (size_t)b * DD * SL + (size_t)dBase * SL;
  bf16* sA = smem;
  bf16* sB1 = smem + 4096;
  bf16* sB2 = smem + 12288;
  f32x4 acc1[4][2] = {}, acc2[4][2] = {};
  for (int k0 = 0; k0 < SL; k0 += 64) {
    stage_t<64>(A + k0, SL, sA, tid);
    stage_t<128>(B1 + k0, SL, sB1, tid);
    stage_t<128>(B2 + k0, SL, sB2, tid);
    __syncthreads();
    compute_64x128x2(sA, sB1, sB2, lane, wave, acc1, acc2);
    __syncthreads();
  }
  const int n15 = lane & 15, quad = lane >> 4;
  const int wn = wave * 32;
  bf16* O1 = qq + (size_t)b * SL * 512 + 256;
  bf16* O2 = kk + (size_t)b * SL * 512 + 256;
#pragma unroll
  for (int ti = 0; ti < 4; ++ti)
#pragma unroll
    for (int tj = 0; tj < 2; ++tj)
#pragma unroll
      for (int r = 0; r < 4; ++r) {
        size_t off = (size_t)(iBase + ti * 16 + quad * 4 + r) * 512 +
                     dBase + wn + tj * 16 + n15;
        O1[off] = __float2bfloat16(acc1[ti][tj][r]);
        O2[off] = __float2bfloat16(acc2[ti][tj][r]);
      }
}

// ---------- K4: attn = tanh(mask(qq.kk^T/16)), K=512; dual store ----------
__global__ __launch_bounds__(256) void k_attn(const bf16* __restrict__ qq,
                                              const bf16* __restrict__ kk,
                                              const int* __restrict__ lens,
                                              float* __restrict__ attn_f32,
                                              bf16* __restrict__ attn_b16)
{
  __shared__ bf16 smem[12288];
  const int tid = threadIdx.x, lane = tid & 63, wave = tid >> 6;
  // grid (16,8,8); swizzle so batch ~ XCD
  const int flat = blockIdx.x + 16 * blockIdx.y + 128 * blockIdx.z;
  const int lid  = (flat & 7) * 128 + (flat >> 3);
  const int bx = lid & 15, by = (lid >> 4) & 7, bz = lid >> 7;
  const int b = bz;
  const int iBase = bx * 64, jBase = by * 128;
  f32x4 acc[4][2] = {};
  gemm_64x128(qq + ((size_t)b * SL + iBase) * 512, 512,
              kk + ((size_t)b * SL + jBase) * 512, 512, 512, smem, tid, acc);
  const int len = lens[b];
  const int n15 = lane & 15, quad = lane >> 4;
  const int wn = wave * 32;
#pragma unroll
  for (int ti = 0; ti < 4; ++ti)
#pragma unroll
    for (int tj = 0; tj < 2; ++tj)
#pragma unroll
      for (int r = 0; r < 4; ++r) {
        int i = iBase + ti * 16 + quad * 4 + r;
        int j = jBase + wn + tj * 16 + n15;
        float vv = (j < len) ? tanh_fast(acc[ti][tj][r] * (1.f / 16.f)) : 0.f;
        size_t idx = (size_t)b * SL * SL + (size_t)i * SL + j;
        attn_f32[idx] = vv;
        attn_b16[idx] = __float2bfloat16(vv);
      }
}

// ---------- K5: fcout = attn @ vpw + q  (fc folded via Wc) ----------
__global__ __launch_bounds__(256) void k_av(const bf16* __restrict__ attn,
                                            const bf16* __restrict__ vpwt,
                                            const float* __restrict__ qres,
                                            float* __restrict__ fcout)
{
  __shared__ bf16 smem[12288];
  const int tid = threadIdx.x, lane = tid & 63, wave = tid >> 6;
  // grid (16,2,8); swizzle so batch ~ XCD
  const int flat = blockIdx.x + 16 * blockIdx.y + 32 * blockIdx.z;
  const int lid  = (flat & 7) * 32 + (flat >> 3);
  const int bx = lid & 15, by = (lid >> 4) & 1, bz = lid >> 5;
  const int b = bz;
  const int iBase = bx * 64, dBase = by * 128;
  f32x4 acc[4][2] = {};
  gemm_64x128(attn + (size_t)b * SL * SL + (size_t)iBase * SL, SL,
              vpwt + (size_t)b * DD * SL + (size_t)dBase * SL, SL, SL, smem, tid, acc);
  const int n15 = lane & 15, quad = lane >> 4;
  const int wn = wave * 32;
#pragma unroll
  for (int ti = 0; ti < 4; ++ti)
#pragma unroll
    for (int tj = 0; tj < 2; ++tj)
#pragma unroll
      for (int r = 0; r < 4; ++r) {
        size_t row = (size_t)b * SL + iBase + ti * 16 + quad * 4 + r;
        int col = dBase + wn + tj * 16 + n15;
        fcout[row * DD + col] = acc[ti][tj][r] + qres[row * DD + col];
      }
}

// ---------- K6: LayerNorm over D=256, one block per row, f32 out ----------
__global__ __launch_bounds__(256) void k_ln(const float* __restrict__ fcout,
                                            const float* __restrict__ gam,
                                            const float* __restrict__ bet,
                                            float* __restrict__ outp)
{
  __shared__ float r1[4], r2[4];
  const int r = blockIdx.x, tid = threadIdx.x;
  const float v = fcout[(size_t)r * DD + tid];
  float s = wred_sum(v), ss = wred_sum(v * v);
  if ((tid & 63) == 0) { r1[tid >> 6] = s; r2[tid >> 6] = ss; }
  __syncthreads();
  s  = r1[0] + r1[1] + r1[2] + r1[3];
  ss = r2[0] + r2[1] + r2[2] + r2[3];
  const float mean = s * (1.f / DD);
  const float var  = ss * (1.f / DD) - mean * mean;
  float y = (v - mean) * rsqrtf(var + 1e-6f);
  y = y * gam[tid] + bet[tid];
  outp[(size_t)r * DD + tid] = y;
}

extern "C" void kernel_launch(void* const* d_in, const int* in_sizes, int n_in,
                              void* d_out, int out_size, void* d_ws, size_t ws_size,
                              hipStream_t stream)
{
  const float* q    = (const float*)d_in[0];
  const float* k    = (const float*)d_in[1];
  const float* v    = (const float*)d_in[2];
  const float* x    = (const float*)d_in[3];
  const int*  lens  = (const int*)d_in[4];
  const float* wqs  = (const float*)d_in[5];
  const float* wks  = (const float*)d_in[6];
  const float* wvs  = (const float*)d_in[7];
  const float* wqs2 = (const float*)d_in[8];
  const float* wks2 = (const float*)d_in[9];
  const float* wfc  = (const float*)d_in[10];
  const float* fi   = (const float*)d_in[11];
  const float* gam  = (const float*)d_in[12];
  const float* bet  = (const float*)d_in[13];

  char* w = (char*)d_ws;
  const size_t MB = 1u << 20;
  bf16* qq    = (bf16*)(w + 0 * MB);    // 8MB: cols 0-255 qp, 256-511 q2f
  bf16* kk    = (bf16*)(w + 8 * MB);    // 8MB: cols 0-255 kp, 256-511 k2f
  bf16* vpwt  = (bf16*)(w + 16 * MB);   // 4MB [b][d][l]  (vpw = v @ Wc^T)
  bf16* q2t   = (bf16*)(w + 20 * MB);   // 4MB [b][d][l]
  bf16* k2t   = (bf16*)(w + 24 * MB);   // 4MB [b][d][l]
  bf16* fa    = (bf16*)(w + 28 * MB);   // 16MB; reused as attn_b16 after k_famul
  bf16* attn_b16 = fa;
  float* Wc   = (float*)(w + 28 * MB);  // 256KB; consumed by k_proj before k_fa overwrites
  float* fcout = (float*)(w + 0 * MB);  // 8MB f32; qq dead after k_attn

  float* outp  = (float*)d_out;                       // (B,L,D) f32
  float* attnp = outp + (size_t)NB * SL * DD;         // (B,L,L) f32

  dim3 blk(256);
  hipLaunchKernelGGL(k_wc,    dim3(256),       blk, 0, stream, wfc, wvs, Wc);
  hipLaunchKernelGGL(k_proj,  dim3(128, 2, 3), blk, 0, stream,
                     q, k, v, wqs, wks, Wc, wqs2, wks2, qq, kk, vpwt, q2t, k2t);
  hipLaunchKernelGGL(k_fa,    dim3(NB * 128),  blk, 0, stream, x, fi, lens, fa);
  hipLaunchKernelGGL(k_famul, dim3(16, 2, 8),  blk, 0, stream, fa, q2t, k2t, qq, kk);
  hipLaunchKernelGGL(k_attn,  dim3(16, 8, 8),  blk, 0, stream,
                     qq, kk, lens, attnp, attn_b16);
  hipLaunchKernelGGL(k_av,    dim3(16, 2, 8),  blk, 0, stream, attn_b16, vpwt, q, fcout);
  hipLaunchKernelGGL(k_ln,    dim3(NB * SL),   blk, 0, stream, fcout, gam, bet, outp);
}

// Round 10
// 205.790 us; speedup vs baseline: 1.0613x; 1.0613x over previous
//
#include <hip/hip_runtime.h>
#include <hip/hip_bf16.h>
#include <math.h>

typedef __hip_bfloat16 bf16;
typedef __bf16 bf16x8 __attribute__((ext_vector_type(8)));
typedef float  f32x4  __attribute__((ext_vector_type(4)));

#define NB 8
#define SL 1024
#define DD 256
#define NF 11
#define RPB 8

#define AS_G __attribute__((address_space(1)))
#define AS_L __attribute__((address_space(3)))

// ---------- fragment loaders ----------
__device__ __forceinline__ bf16x8 ldfrag(const bf16* p) {
  return *reinterpret_cast<const bf16x8*>(p);
}
__device__ __forceinline__ bf16x8 ldfrag(const float* p) {
  const float4 a = *reinterpret_cast<const float4*>(p);
  const float4 b = *reinterpret_cast<const float4*>(p + 4);
  bf16x8 r;
  r[0] = (__bf16)a.x; r[1] = (__bf16)a.y; r[2] = (__bf16)a.z; r[3] = (__bf16)a.w;
  r[4] = (__bf16)b.x; r[5] = (__bf16)b.y; r[6] = (__bf16)b.z; r[7] = (__bf16)b.w;
  return r;
}
__device__ __forceinline__ unsigned short us(float f) {
  bf16 h = __float2bfloat16(f);
  return *reinterpret_cast<unsigned short*>(&h);
}
__device__ __forceinline__ float tanh_fast(float x) {
  return 1.f - 2.f / (__expf(2.f * x) + 1.f);
}

// ---------- stage R rows x 64 k into XOR-swizzled LDS ----------
// f32 source: sync VGPR convert
template<int R>
__device__ __forceinline__ void stage_t(const float* __restrict__ g, int ld,
                                        bf16* __restrict__ s, int tid) {
#pragma unroll
  for (int it = 0; it < R / 32; ++it) {
    const int cid = it * 256 + tid;
    const int row = cid >> 3, c16 = cid & 7;
    bf16x8 v = ldfrag(g + (size_t)row * ld + c16 * 8);
    *reinterpret_cast<bf16x8*>(s + row * 64 + ((c16 ^ (row & 7)) << 3)) = v;
  }
}
// bf16 source: async global_load_lds, swizzle folded into source addr
template<int R>
__device__ __forceinline__ void stage_t(const bf16* __restrict__ g, int ld,
                                        bf16* __restrict__ s, int tid) {
  const int wbase = tid & ~63;
#pragma unroll
  for (int it = 0; it < R / 32; ++it) {
    const int cid = it * 256 + tid;
    const int row = cid >> 3, sc = cid & 7;
    const int c16 = sc ^ (row & 7);
    const bf16* src = g + (size_t)row * ld + c16 * 8;
    bf16* dst = s + (size_t)(it * 256 + wbase) * 8;
    __builtin_amdgcn_global_load_lds((const AS_G void*)src, (AS_L void*)dst, 16, 0, 0);
  }
}

// ---------- compute: 64x128 tile (4 waves x 64x32) from sA 64x64 + sB 128x64 ----------
__device__ __forceinline__ void compute_64x128(const bf16* __restrict__ sA,
                                               const bf16* __restrict__ sB,
                                               int lane, int wave, f32x4 acc[4][2]) {
  const int n15 = lane & 15, quad = lane >> 4;
  const int wn = wave * 32;
#pragma unroll
  for (int kc = 0; kc < 2; ++kc) {
    const int c16 = kc * 4 + quad;
    bf16x8 aF[4], bF[2];
#pragma unroll
    for (int t = 0; t < 4; ++t) {
      const int ra = t * 16 + n15;
      aF[t] = *reinterpret_cast<const bf16x8*>(sA + ra * 64 + ((c16 ^ (ra & 7)) << 3));
    }
#pragma unroll
    for (int t = 0; t < 2; ++t) {
      const int rb = wn + t * 16 + n15;
      bF[t] = *reinterpret_cast<const bf16x8*>(sB + rb * 64 + ((c16 ^ (rb & 7)) << 3));
    }
#pragma unroll
    for (int ti = 0; ti < 4; ++ti)
#pragma unroll
      for (int tj = 0; tj < 2; ++tj)
        acc[ti][tj] = __builtin_amdgcn_mfma_f32_16x16x32_bf16(aF[ti], bF[tj], acc[ti][tj], 0, 0, 0);
  }
}

// ---------- GEMM driver: C(64x128) += A(64xK) * B(128xK)^T, single-buffer ----------
template<typename TA, typename TB>
__device__ __forceinline__ void gemm_64x128(const TA* __restrict__ A, int lda,
                                            const TB* __restrict__ B, int ldb, int K,
                                            bf16* s, int tid, f32x4 acc[4][2]) {
  const int lane = tid & 63, wave = tid >> 6;
  bf16* sA = s;
  bf16* sB = s + 4096;
  for (int k0 = 0; k0 < K; k0 += 64) {
    stage_t<64>(A + k0, lda, sA, tid);
    stage_t<128>(B + k0, ldb, sB, tid);
    __syncthreads();
    compute_64x128(sA, sB, lane, wave, acc);
    __syncthreads();
  }
}

__device__ __forceinline__ float wred_sum(float v) {
#pragma unroll
  for (int o = 32; o > 0; o >>= 1) v += __shfl_xor(v, o, 64);
  return v;
}

// ---------- K0: prep — convert q,k,v to bf16 AND compute Wc = w_fc @ w_vs ----------
__global__ __launch_bounds__(256) void k_prep(const float* __restrict__ q,
                                              const float* __restrict__ k,
                                              const float* __restrict__ v,
                                              const float* __restrict__ wfc,
                                              const float* __restrict__ wvs,
                                              bf16* __restrict__ cq,
                                              bf16* __restrict__ ck,
                                              bf16* __restrict__ cv,
                                              float* __restrict__ Wc)
{
  const int bid = blockIdx.x, tid = threadIdx.x;
  if (bid < 1536) {
    // convert: 3 tensors x 512 blocks each; 4 float4 per thread
    const int which = bid >> 9, sub = bid & 511;
    const float* src = (which == 0) ? q : (which == 1) ? k : v;
    bf16* dst = (which == 0) ? cq : (which == 1) ? ck : cv;
    const size_t base = (size_t)sub * 4096;
#pragma unroll
    for (int it = 0; it < 4; ++it) {
      const size_t off = base + (size_t)(it * 256 + tid) * 4;
      const float4 a = *reinterpret_cast<const float4*>(src + off);
      ushort4 pk = make_ushort4(us(a.x), us(a.y), us(a.z), us(a.w));
      *reinterpret_cast<ushort4*>(dst + off) = pk;
    }
  } else {
    // Wc row o = bid - 1536
    const int o = bid - 1536, m = tid;
    const float* fr = wfc + (size_t)o * DD;
    float acc = 0.f;
#pragma unroll 8
    for (int i = 0; i < DD; ++i)
      acc += fr[i] * wvs[(size_t)i * DD + m];
    Wc[(size_t)o * DD + m] = acc;
  }
}

// ---------- K1: 5 projections (bf16 A via async DMA, f32 W sync) ----------
__global__ __launch_bounds__(256) void k_proj(
    const bf16* __restrict__ cq, const bf16* __restrict__ ck, const bf16* __restrict__ cv,
    const float* __restrict__ wqs, const float* __restrict__ wks, const float* __restrict__ Wc,
    const float* __restrict__ wqs2, const float* __restrict__ wks2,
    bf16* __restrict__ qq, bf16* __restrict__ kk,
    bf16* __restrict__ vpwt, bf16* __restrict__ q2t, bf16* __restrict__ k2t)
{
  __shared__ bf16 smem[12288];
  const int tid = threadIdx.x, lane = tid & 63, wave = tid >> 6;
  const int z = blockIdx.z;
  const bf16*  A = (z == 2) ? cv : ((z == 1 || z == 4) ? ck : cq);
  const float* W = (z == 0) ? wqs : (z == 1) ? wks : (z == 2) ? Wc : (z == 3) ? wqs2 : wks2;
  const int rowBase = blockIdx.x * 64;
  const int colBase = blockIdx.y * 128;
  f32x4 acc[4][2] = {};
  gemm_64x128(A + (size_t)rowBase * DD, DD, W + (size_t)colBase * DD, DD, DD, smem, tid, acc);
  const int n15 = lane & 15, quad = lane >> 4;
  const int wn = wave * 32;
  if (z <= 1) {
    bf16* O = (z == 0) ? qq : kk;
#pragma unroll
    for (int ti = 0; ti < 4; ++ti)
#pragma unroll
      for (int tj = 0; tj < 2; ++tj)
#pragma unroll
        for (int r = 0; r < 4; ++r) {
          int row = rowBase + ti * 16 + quad * 4 + r;
          int col = colBase + wn + tj * 16 + n15;
          O[(size_t)row * 512 + col] = __float2bfloat16(acc[ti][tj][r]);
        }
  } else {
    bf16* O = (z == 2) ? vpwt : (z == 3) ? q2t : k2t;
    const int bb = rowBase >> 10, rowInB = rowBase & 1023;
#pragma unroll
    for (int ti = 0; ti < 4; ++ti)
#pragma unroll
      for (int tj = 0; tj < 2; ++tj) {
        int l0  = rowInB + ti * 16 + quad * 4;
        int col = colBase + wn + tj * 16 + n15;
        ushort4 pk = make_ushort4(us(acc[ti][tj][0]), us(acc[ti][tj][1]),
                                  us(acc[ti][tj][2]), us(acc[ti][tj][3]));
        *reinterpret_cast<ushort4*>(&O[((size_t)bb * DD + col) * SL + l0]) = pk;
      }
  }
}

// ---------- K2: feature-affinity softmax, RPB rows per block ----------
__global__ __launch_bounds__(256) void k_fa(const float* __restrict__ x,
                                            const float* __restrict__ fi_g,
                                            const int* __restrict__ lens,
                                            bf16* __restrict__ fa)
{
  __shared__ __align__(16) float sx[SL * NF];
  __shared__ float sredS[4][RPB];
  const int tid = threadIdx.x, wave = tid >> 6;
  const int b  = blockIdx.x >> 7;
  const int i0 = (blockIdx.x & 127) * RPB;
  {
    const float4* src = reinterpret_cast<const float4*>(x + (size_t)b * SL * NF);
    float4* dst = reinterpret_cast<float4*>(sx);
#pragma unroll
    for (int it = 0; it < 11; ++it) dst[it * 256 + tid] = src[it * 256 + tid];
  }
  float fiv[NF];
#pragma unroll
  for (int f = 0; f < NF; ++f) fiv[f] = fi_g[f];
  const int len = lens[b];
  __syncthreads();
  float xi[RPB][NF];
#pragma unroll
  for (int i = 0; i < RPB; ++i)
#pragma unroll
    for (int f = 0; f < NF; ++f) xi[i][f] = sx[(i0 + i) * NF + f];
  float e[RPB][4];
  float ps[RPB];
#pragma unroll
  for (int i = 0; i < RPB; ++i) ps[i] = 0.f;
#pragma unroll
  for (int t = 0; t < 4; ++t) {
    const int j = tid + t * 256;
    const bool valid = (t < 2) || (j < len);
    float xj[NF];
#pragma unroll
    for (int f = 0; f < NF; ++f) xj[f] = sx[j * NF + f];
#pragma unroll
    for (int i = 0; i < RPB; ++i) {
      float a = 0.f;
#pragma unroll
      for (int f = 0; f < NF; ++f) a += fabsf(xi[i][f] - xj[f]) * fiv[f];
      float ev = valid ? __expf(a) : 0.f;
      e[i][t] = ev;
      ps[i] += ev;
    }
  }
#pragma unroll
  for (int i = 0; i < RPB; ++i) {
    float wsv = wred_sum(ps[i]);
    if ((tid & 63) == 0) sredS[wave][i] = wsv;
  }
  __syncthreads();
  bf16* out = fa + (size_t)b * SL * SL + (size_t)i0 * SL;
#pragma unroll
  for (int i = 0; i < RPB; ++i) {
    const float inv = 1.f / (sredS[0][i] + sredS[1][i] + sredS[2][i] + sredS[3][i]);
#pragma unroll
    for (int t = 0; t < 4; ++t)
      out[(size_t)i * SL + tid + t * 256] = __float2bfloat16(e[i][t] * inv);
  }
}

// ---------- K3: q2f/k2f = fa @ {q2,k2} -> qq/kk cols 256..511 ----------
__global__ __launch_bounds__(256) void k_famul(const bf16* __restrict__ fa,
                                               const bf16* __restrict__ q2t,
                                               const bf16* __restrict__ k2t,
                                               bf16* __restrict__ qq,
                                               bf16* __restrict__ kk)
{
  __shared__ bf16 smem[12288];
  const int tid = threadIdx.x, lane = tid & 63, wave = tid >> 6;
  // grid (16,2,16); swizzle so batch ~ XCD
  const int flat = blockIdx.x + 16 * blockIdx.y + 32 * blockIdx.z;
  const int lid  = (flat & 7) * 64 + (flat >> 3);
  const int bx = lid & 15, by = (lid >> 4) & 1, bz = lid >> 5;
  const int b = bz >> 1, which = bz & 1;
  const int iBase = bx * 64, dBase = by * 128;
  const bf16* A  = fa + (size_t)b * SL * SL + (size_t)iBase * SL;
  const bf16* Bm = (which ? k2t : q2t) + (size_t)b * DD * SL + (size_t)dBase * SL;
  f32x4 acc[4][2] = {};
  gemm_64x128(A, SL, Bm, SL, SL, smem, tid, acc);
  bf16* O = (which ? kk : qq) + (size_t)b * SL * 512 + 256;
  const int n15 = lane & 15, quad = lane >> 4;
  const int wn = wave * 32;
#pragma unroll
  for (int ti = 0; ti < 4; ++ti)
#pragma unroll
    for (int tj = 0; tj < 2; ++tj)
#pragma unroll
      for (int r = 0; r < 4; ++r)
        O[(size_t)(iBase + ti * 16 + quad * 4 + r) * 512 +
          dBase + wn + tj * 16 + n15] = __float2bfloat16(acc[ti][tj][r]);
}

// ---------- K4: attn = tanh(mask(qq.kk^T/16)), K=512; dual store ----------
__global__ __launch_bounds__(256) void k_attn(const bf16* __restrict__ qq,
                                              const bf16* __restrict__ kk,
                                              const int* __restrict__ lens,
                                              float* __restrict__ attn_f32,
                                              bf16* __restrict__ attn_b16)
{
  __shared__ bf16 smem[12288];
  const int tid = threadIdx.x, lane = tid & 63, wave = tid >> 6;
  // grid (16,8,8); swizzle so batch ~ XCD
  const int flat = blockIdx.x + 16 * blockIdx.y + 128 * blockIdx.z;
  const int lid  = (flat & 7) * 128 + (flat >> 3);
  const int bx = lid & 15, by = (lid >> 4) & 7, bz = lid >> 7;
  const int b = bz;
  const int iBase = bx * 64, jBase = by * 128;
  f32x4 acc[4][2] = {};
  gemm_64x128(qq + ((size_t)b * SL + iBase) * 512, 512,
              kk + ((size_t)b * SL + jBase) * 512, 512, 512, smem, tid, acc);
  const int len = lens[b];
  const int n15 = lane & 15, quad = lane >> 4;
  const int wn = wave * 32;
#pragma unroll
  for (int ti = 0; ti < 4; ++ti)
#pragma unroll
    for (int tj = 0; tj < 2; ++tj)
#pragma unroll
      for (int r = 0; r < 4; ++r) {
        int i = iBase + ti * 16 + quad * 4 + r;
        int j = jBase + wn + tj * 16 + n15;
        float vv = (j < len) ? tanh_fast(acc[ti][tj][r] * (1.f / 16.f)) : 0.f;
        size_t idx = (size_t)b * SL * SL + (size_t)i * SL + j;
        attn_f32[idx] = vv;
        attn_b16[idx] = __float2bfloat16(vv);
      }
}

// ---------- K5: fcout = attn @ vpw + q  (fc folded via Wc) ----------
__global__ __launch_bounds__(256) void k_av(const bf16* __restrict__ attn,
                                            const bf16* __restrict__ vpwt,
                                            const float* __restrict__ qres,
                                            float* __restrict__ fcout)
{
  __shared__ bf16 smem[12288];
  const int tid = threadIdx.x, lane = tid & 63, wave = tid >> 6;
  // grid (16,2,8); swizzle so batch ~ XCD
  const int flat = blockIdx.x + 16 * blockIdx.y + 32 * blockIdx.z;
  const int lid  = (flat & 7) * 32 + (flat >> 3);
  const int bx = lid & 15, by = (lid >> 4) & 1, bz = lid >> 5;
  const int b = bz;
  const int iBase = bx * 64, dBase = by * 128;
  f32x4 acc[4][2] = {};
  gemm_64x128(attn + (size_t)b * SL * SL + (size_t)iBase * SL, SL,
              vpwt + (size_t)b * DD * SL + (size_t)dBase * SL, SL, SL, smem, tid, acc);
  const int n15 = lane & 15, quad = lane >> 4;
  const int wn = wave * 32;
#pragma unroll
  for (int ti = 0; ti < 4; ++ti)
#pragma unroll
    for (int tj = 0; tj < 2; ++tj)
#pragma unroll
      for (int r = 0; r < 4; ++r) {
        size_t row = (size_t)b * SL + iBase + ti * 16 + quad * 4 + r;
        int col = dBase + wn + tj * 16 + n15;
        fcout[row * DD + col] = acc[ti][tj][r] + qres[row * DD + col];
      }
}

// ---------- K6: LayerNorm over D=256, one block per row, f32 out ----------
__global__ __launch_bounds__(256) void k_ln(const float* __restrict__ fcout,
                                            const float* __restrict__ gam,
                                            const float* __restrict__ bet,
                                            float* __restrict__ outp)
{
  __shared__ float r1[4], r2[4];
  const int r = blockIdx.x, tid = threadIdx.x;
  const float v = fcout[(size_t)r * DD + tid];
  float s = wred_sum(v), ss = wred_sum(v * v);
  if ((tid & 63) == 0) { r1[tid >> 6] = s; r2[tid >> 6] = ss; }
  __syncthreads();
  s  = r1[0] + r1[1] + r1[2] + r1[3];
  ss = r2[0] + r2[1] + r2[2] + r2[3];
  const float mean = s * (1.f / DD);
  const float var  = ss * (1.f / DD) - mean * mean;
  float y = (v - mean) * rsqrtf(var + 1e-6f);
  y = y * gam[tid] + bet[tid];
  outp[(size_t)r * DD + tid] = y;
}

extern "C" void kernel_launch(void* const* d_in, const int* in_sizes, int n_in,
                              void* d_out, int out_size, void* d_ws, size_t ws_size,
                              hipStream_t stream)
{
  const float* q    = (const float*)d_in[0];
  const float* k    = (const float*)d_in[1];
  const float* v    = (const float*)d_in[2];
  const float* x    = (const float*)d_in[3];
  const int*  lens  = (const int*)d_in[4];
  const float* wqs  = (const float*)d_in[5];
  const float* wks  = (const float*)d_in[6];
  const float* wvs  = (const float*)d_in[7];
  const float* wqs2 = (const float*)d_in[8];
  const float* wks2 = (const float*)d_in[9];
  const float* wfc  = (const float*)d_in[10];
  const float* fi   = (const float*)d_in[11];
  const float* gam  = (const float*)d_in[12];
  const float* bet  = (const float*)d_in[13];

  char* w = (char*)d_ws;
  const size_t MB = 1u << 20;
  const size_t KB = 1u << 10;
  bf16* qq    = (bf16*)(w + 0 * MB);    // 8MB: cols 0-255 qp, 256-511 q2f
  bf16* kk    = (bf16*)(w + 8 * MB);    // 8MB: cols 0-255 kp, 256-511 k2f
  bf16* vpwt  = (bf16*)(w + 16 * MB);   // 4MB [b][d][l]  (vpw = v @ Wc^T)
  bf16* q2t   = (bf16*)(w + 20 * MB);   // 4MB [b][d][l]
  bf16* k2t   = (bf16*)(w + 24 * MB);   // 4MB [b][d][l]
  // 28..44MB region is time-multiplexed:
  //   phase 1 (k_prep/k_proj): cq, ck, cv (12MB) + Wc (256KB at 40MB)
  //   phase 2 (k_fa onward):   fa / attn_b16 (16MB)
  bf16* cq    = (bf16*)(w + 28 * MB);
  bf16* ck    = (bf16*)(w + 32 * MB);
  bf16* cv    = (bf16*)(w + 36 * MB);
  float* Wc   = (float*)(w + 40 * MB);
  bf16* fa    = (bf16*)(w + 28 * MB);
  bf16* attn_b16 = fa;
  float* fcout = (float*)(w + 0 * MB);  // 8MB f32; qq dead after k_attn

  float* outp  = (float*)d_out;                       // (B,L,D) f32
  float* attnp = outp + (size_t)NB * SL * DD;         // (B,L,L) f32
  (void)KB; (void)wvs;

  dim3 blk(256);
  hipLaunchKernelGGL(k_prep,  dim3(1792),      blk, 0, stream, q, k, v, wfc, wvs,
                     cq, ck, cv, Wc);
  hipLaunchKernelGGL(k_proj,  dim3(128, 2, 5), blk, 0, stream,
                     cq, ck, cv, wqs, wks, Wc, wqs2, wks2, qq, kk, vpwt, q2t, k2t);
  hipLaunchKernelGGL(k_fa,    dim3(NB * 128),  blk, 0, stream, x, fi, lens, fa);
  hipLaunchKernelGGL(k_famul, dim3(16, 2, 16), blk, 0, stream, fa, q2t, k2t, qq, kk);
  hipLaunchKernelGGL(k_attn,  dim3(16, 8, 8),  blk, 0, stream,
                     qq, kk, lens, attnp, attn_b16);
  hipLaunchKernelGGL(k_av,    dim3(16, 2, 8),  blk, 0, stream, attn_b16, vpwt, q, fcout);
  hipLaunchKernelGGL(k_ln,    dim3(NB * SL),   blk, 0, stream, fcout, gam, bet, outp);
}